// Round 2
// baseline (2694.831 us; speedup 1.0000x reference)
//
#include <hip/hip_runtime.h>

// TrajectoryDecoder r8 = r7 resubmit (r7 bench died to container infra, no verdict).
// Dual-chain software pipelining.
// r6 rocprof: MfmaUtil 24.9, VALUBusy 54.3, HBM ~0 — lockstep 8-wave block
// serializes the MFMA K-loop and the VALU gate phase across barriers; the two
// pipes never overlap. r7/r8: each 512-thr block runs TWO independent 32-seq GRU
// chains, phase-shifted by one barrier interval:
//   I1 = { Kloop_B(t) MFMA || phaseB_A(t) VALU || phaseC_B(t-1) } ; bar
//   I2 = { Kloop_A(t+1)    || phaseB_B(t)      || phaseC_A(t)   } ; bar
// The same 2 lgkm-barriers serve both chains (barrier cost per chain-step
// halves) and each K-loop's MFMAs drain under the other chain's VALU phase.
// Register budget (256/wave @ 2 waves/SIMD): 96 acc (AGPR) + 32 f32 h-state +
// temps; wR/wZ stream from L2 explicitly in-loop (r6's VGPR=120 < 128 proves
// they were never resident anyway). wN: 14/16 k-slices in LDS, 2 stream from
// L2, so 2x Hb fits: LDS = 157,184 B. h in f32 regs drops 16 ds_read_u16+bf2f
// per interval. Grid 768 (64 seqs/block), 3 rounds/CU.
// All per-chain math (layouts, phase B, DPP delta, phase C, corr) is r6-verified.

typedef __attribute__((ext_vector_type(8))) short short8;
typedef __bf16 bf16x8 __attribute__((ext_vector_type(8)));
typedef float f32x16 __attribute__((ext_vector_type(16)));
typedef float f32x4 __attribute__((ext_vector_type(4)));

#define HSTR 264               // Hb stride (bf16): 528B rows; balanced banks
#define NSEQ 32                // seqs per chain (2 chains per block)
#define WNL_SLICES 14          // wN k-slices staged in LDS (ks 14,15 from L2)
#define WHH3_ELEMS (24 * 16 * 64 * 8)  // 196608 = 768x256
#define WH0_ELEMS (8 * 20 * 64 * 8)    // 81920

static __device__ __forceinline__ unsigned short f2bf(float f) {
  unsigned u = __builtin_bit_cast(unsigned, f);
  u += 0x7fffu + ((u >> 16) & 1u);   // RNE
  return (unsigned short)(u >> 16);
}
static __device__ __forceinline__ bf16x8 ldfrag(const unsigned short* p) {
  return __builtin_bit_cast(bf16x8, *(const short8*)p);
}
static __device__ __forceinline__ float fsig(float x) {
  return __builtin_amdgcn_rcpf(1.f + __builtin_amdgcn_exp2f(-1.44269504f * x));
}
static __device__ __forceinline__ float ftanh(float x) {
  return 1.f - 2.f * __builtin_amdgcn_rcpf(1.f + __builtin_amdgcn_exp2f(2.88539008f * x));
}
static __device__ __forceinline__ float dpp16sum(float x) {
  x += __builtin_bit_cast(float, __builtin_amdgcn_update_dpp(0, __builtin_bit_cast(int, x), 0xB1, 0xF, 0xF, true));
  x += __builtin_bit_cast(float, __builtin_amdgcn_update_dpp(0, __builtin_bit_cast(int, x), 0x4E, 0xF, 0xF, true));
  x += __builtin_bit_cast(float, __builtin_amdgcn_update_dpp(0, __builtin_bit_cast(int, x), 0x141, 0xF, 0xF, true));
  x += __builtin_bit_cast(float, __builtin_amdgcn_update_dpp(0, __builtin_bit_cast(int, x), 0x140, 0xF, 0xF, true));
  return x;
}
// LDS-only barrier (r4-verified): no vmcnt drain; t-loop vmem = weight loads
// (compiler-waited before MFMA use) + out stores (fire-and-forget).
static __device__ __forceinline__ void bar_lgkm() {
  asm volatile("s_waitcnt lgkmcnt(0)\n\ts_barrier" ::: "memory");
}

// ---- prep: pack W_hh slice-major: [(g*8+w)*16 + ks][lane][8]  (r3-verified) ----
__global__ void prep_whh3_k(const float* __restrict__ Whh, unsigned short* __restrict__ Whhp3) {
  int i = blockIdx.x * 256 + threadIdx.x;
  if (i >= WHH3_ELEMS) return;
  int j = i & 7;
  int lane = (i >> 3) & 63;
  int rest = i >> 9;
  int ks = rest & 15;
  int sw = rest >> 4;
  int g = sw >> 3, w = sw & 7;
  int row = g * 256 + w * 32 + (lane & 31);
  int k = ks * 16 + ((lane >> 5) << 3) + j;
  Whhp3[i] = f2bf(Whh[row * 256 + k]);
}

// ---- prep: pack W_h0 (256 x 290, K padded to 320)  (r3-verified) ----
__global__ void prep_wh0_k(const float* __restrict__ Wh0, unsigned short* __restrict__ Wh0p) {
  int i = blockIdx.x * 256 + threadIdx.x;
  if (i >= WH0_ELEMS) return;
  int j = i & 7;
  int lane = (i >> 3) & 63;
  int rest = i >> 9;
  int ks = rest % 20;
  int nt = rest / 20;
  int row = nt * 32 + (lane & 31);
  int k = ks * 16 + ((lane >> 5) << 3) + j;
  float v = (k < 290) ? Wh0[row * 290 + k] : 0.f;
  Wh0p[i] = f2bf(v);
}

// ---- prep: per-h-unit params (r3-verified) ----
__global__ void prep_gp_k(const float* __restrict__ bih, const float* __restrict__ bhh,
                          const float* __restrict__ Wih, const float* __restrict__ Wout,
                          float* __restrict__ gpo) {
  int n = threadIdx.x;
  gpo[n * 12 + 0]  = bih[n] + bhh[n];
  gpo[n * 12 + 1]  = bih[n + 256] + bhh[n + 256];
  gpo[n * 12 + 2]  = bih[n + 512];
  gpo[n * 12 + 3]  = bhh[n + 512];
  gpo[n * 12 + 4]  = Wih[n * 2 + 0];
  gpo[n * 12 + 5]  = Wih[n * 2 + 1];
  gpo[n * 12 + 6]  = Wih[(n + 256) * 2 + 0];
  gpo[n * 12 + 7]  = Wih[(n + 256) * 2 + 1];
  gpo[n * 12 + 8]  = Wih[(n + 512) * 2 + 0];
  gpo[n * 12 + 9]  = Wih[(n + 512) * 2 + 1];
  gpo[n * 12 + 10] = Wout[n];
  gpo[n * 12 + 11] = Wout[256 + n];
}

// ---------------- main fused GRU, dual-chain pipelined ----------------
__global__ __launch_bounds__(512, 2) void gru_main_k(
    const float* __restrict__ ctx, const float* __restrict__ goals,
    const float* __restrict__ emb, const float* __restrict__ bh0,
    const float* __restrict__ bout,
    const unsigned short* __restrict__ Wh0p,
    const unsigned short* __restrict__ Whhp3,
    const float* __restrict__ gp,
    float* __restrict__ out) {
  __shared__ __align__(16) unsigned short wNl[8 * WNL_SLICES * 64 * 8]; // 114688 B
  __shared__ __align__(16) unsigned short HbA[NSEQ * HSTR];            // 16896 B
  __shared__ __align__(16) unsigned short HbB[NSEQ * HSTR];            // 16896 B
  __shared__ __align__(16) float dpartA[16 * NSEQ * 2];                // 4096 B
  __shared__ __align__(16) float dpartB[16 * NSEQ * 2];                // 4096 B
  __shared__ __align__(16) float posA[NSEQ * 2];                       // 256 B
  __shared__ __align__(16) float posB[NSEQ * 2];                       // 256 B
  // total 157,184 B <= 160 KiB; 1 block/CU, 8 waves (2/SIMD)

  const int tid = threadIdx.x;
  const int w = tid >> 6;
  const int l = tid & 63;
  const int l31 = l & 31;
  const int grp = l >> 5;
  const int seq0 = blockIdx.x * (2 * NSEQ);
  const int n0 = w * 32 + l31;

  // ---- stage wN slices 0..13 per wave into LDS, block-cooperative ----
  {
    short8* wdst = (short8*)wNl;
    const short8* wsrc = (const short8*)Whhp3;
    for (int f = tid; f < 8 * WNL_SLICES * 64; f += 512) {
      int ll = f & 63;
      int t2 = f >> 6;
      int ks = t2 % WNL_SLICES;
      int ww = t2 / WNL_SLICES;
      wdst[f] = wsrc[((16 + ww) * 16 + ks) * 64 + ll];   // g=2 region
    }
  }

  // ---------------- Phase 0: h0 = init_in @ W_h0^T + b_h0 (per chain) ----------------
  auto phase0 = [&](unsigned short* Hb, int sBase, f32x16& acc0) {
    unsigned short* As = Hb;   // overlay staging, stride 176 (5632 shorts < 8448)
    for (int cc = 0; cc < 2; ++cc) {
      for (int i = tid; i < NSEQ * 160; i += 512) {
        int row = i / 160;
        int col = i - row * 160;
        int d = cc * 160 + col;
        int s = sBase + row;
        int b = s / 6;
        float v;
        if (d < 256)      v = ctx[b * 256 + d];
        else if (d < 258) v = goals[s * 2 + (d - 256)];
        else if (d < 290) v = emb[b * 32 + (d - 258)];
        else              v = 0.f;
        As[row * 176 + col] = f2bf(v);
      }
      __syncthreads();   // also orders wNl staging (first pass)
      for (int ks = 0; ks < 10; ++ks) {
        bf16x8 bf = ldfrag(&Wh0p[((w * 20 + cc * 10 + ks) * 64 + l) * 8]);
        bf16x8 af = ldfrag(&As[l31 * 176 + ks * 16 + grp * 8]);
        acc0 = __builtin_amdgcn_mfma_f32_32x32x16_bf16(af, bf, acc0, 0, 0, 0);
      }
      __syncthreads();
    }
  };

  f32x16 acc0A = f32x16{}, acc0B = f32x16{};
  phase0(HbA, seq0, acc0A);
  phase0(HbB, seq0 + NSEQ, acc0B);

  float hA[16], hB[16];
  {
    float b0 = bh0[n0];
#pragma unroll
    for (int r = 0; r < 16; ++r) {
      int row = (r & 3) + 8 * (r >> 2) + 4 * grp;   // C/D layout [m74/m101]
      hA[r] = acc0A[r] + b0;
      hB[r] = acc0B[r] + b0;
      HbA[row * HSTR + n0] = f2bf(hA[r]);
      HbB[row * HSTR + n0] = f2bf(hB[r]);
    }
  }
  if (tid < 2 * NSEQ) { posA[tid] = 0.f; posB[tid] = 0.f; }

  float brr, bzz, bin_, bhn, wr0, wr1, wz0, wz1, wn0, wn1, wo0, wo1;
  {
    f32x4 g0 = *(const f32x4*)&gp[n0 * 12];
    f32x4 g1 = *(const f32x4*)&gp[n0 * 12 + 4];
    f32x4 g2 = *(const f32x4*)&gp[n0 * 12 + 8];
    brr = g0[0]; bzz = g0[1]; bin_ = g0[2]; bhn = g0[3];
    wr0 = g1[0]; wr1 = g1[1]; wz0 = g1[2]; wz1 = g1[3];
    wn0 = g2[0]; wn1 = g2[1]; wo0 = g2[2]; wo1 = g2[3];
  }
  const float bo0 = bout[0], bo1 = bout[1];
  __syncthreads();   // h0 writes + pos init visible to all

  // Per-wave weight-stream base pointers (L2-resident, 393 KB set)
  const unsigned short* wRb = &Whhp3[((w * 16) * 64 + l) * 8];          // g=0
  const unsigned short* wZb = &Whhp3[(((8 + w) * 16) * 64 + l) * 8];    // g=1
  const unsigned short* wNg = &Whhp3[(((16 + w) * 16) * 64 + l) * 8];   // g=2

  // K-loop: A from Hb (LDS), wR/wZ streamed from L2, wN from LDS (+2 slices L2)
  auto kloop = [&](const unsigned short* Hb, f32x16& ar, f32x16& az, f32x16& an) {
    ar = f32x16{}; az = f32x16{}; an = f32x16{};
#pragma unroll
    for (int ks = 0; ks < 16; ++ks) {
      bf16x8 af = ldfrag(&Hb[l31 * HSTR + ks * 16 + grp * 8]);
      bf16x8 bR = ldfrag(&wRb[ks * 512]);
      bf16x8 bZ = ldfrag(&wZb[ks * 512]);
      bf16x8 bN = (ks < WNL_SLICES)
          ? ldfrag(&wNl[((w * WNL_SLICES + ks) * 64 + l) * 8])
          : ldfrag(&wNg[ks * 512]);
      ar = __builtin_amdgcn_mfma_f32_32x32x16_bf16(af, bR, ar, 0, 0, 0);
      az = __builtin_amdgcn_mfma_f32_32x32x16_bf16(af, bZ, az, 0, 0, 0);
      an = __builtin_amdgcn_mfma_f32_32x32x16_bf16(af, bN, an, 0, 0, 0);
    }
  };

  // Phase B: gates + h update (h in f32 regs) + delta partials (r3-verified)
  auto phaseB = [&](const f32x16& ar, const f32x16& az, const f32x16& an,
                    float* posL, unsigned short* Hb, float* dpart, float (&h)[16]) {
#pragma unroll
    for (int q2 = 0; q2 < 4; ++q2) {
      int sb = 8 * q2 + 4 * grp;
      f32x4 xyA = *(const f32x4*)&posL[sb * 2];
      f32x4 xyB = *(const f32x4*)&posL[sb * 2 + 4];
#pragma unroll
      for (int e = 0; e < 4; ++e) {
        int r = 4 * q2 + e;
        int s = sb + e;
        float x = (e == 0) ? xyA[0] : (e == 1) ? xyA[2] : (e == 2) ? xyB[0] : xyB[2];
        float y = (e == 0) ? xyA[1] : (e == 1) ? xyA[3] : (e == 2) ? xyB[1] : xyB[3];
        float rg = fsig(ar[r] + brr + x * wr0 + y * wr1);
        float zg = fsig(az[r] + bzz + x * wz0 + y * wz1);
        float ng = ftanh(fmaf(rg, an[r] + bhn, fmaf(x, wn0, fmaf(y, wn1, bin_))));
        float hnew = fmaf(zg, h[r] - ng, ng);     // (1-z)*n + z*h
        h[r] = hnew;
        Hb[s * HSTR + n0] = f2bf(hnew);
        float dx = dpp16sum(hnew * wo0);
        float dy = dpp16sum(hnew * wo1);
        if ((l & 15) == 0) {
          int p16 = w * 2 + ((l >> 4) & 1);
          dpart[(p16 * NSEQ + s) * 2]     = dx;
          dpart[(p16 * NSEQ + s) * 2 + 1] = dy;
        }
      }
    }
  };

  // Phase C (one wave per chain): pos update + raw pred store
  auto phaseC = [&](float* posL, float* dpart, int sBase, int st, int tbase) {
    int tt = tid - tbase;
    if (tt >= 0 && tt < 2 * NSEQ) {
      int s = tt >> 1, c = tt & 1;
      float d = (c == 0) ? bo0 : bo1;
#pragma unroll
      for (int q = 0; q < 16; ++q) d += dpart[(q * NSEQ + s) * 2 + c];
      float p = posL[tt] + d;
      posL[tt] = p;
      out[((sBase + s) * 30 + st) * 2 + c] = p;
    }
  };

  // ---------------- T recurrent steps, dual-chain pipelined ----------------
  f32x16 arA, azA, anA, arB, azB, anB;
  kloop(HbA, arA, azA, anA);              // Kloop_A(0)

#pragma unroll 1
  for (int t = 0; t < 30; ++t) {
    // I1: Kloop_B(t) MFMA || phaseC_B(t-1) || phaseB_A(t) VALU
    kloop(HbB, arB, azB, anB);
    if (t > 0) phaseC(posB, dpartB, seq0 + NSEQ, t - 1, 64);
    phaseB(arA, azA, anA, posA, HbA, dpartA, hA);
    bar_lgkm();   // HbA writes + dpartA visible; Kloop_B reads of HbB retired
    // I2: Kloop_A(t+1) MFMA || phaseC_A(t) || phaseB_B(t) VALU
    if (t < 29) kloop(HbA, arA, azA, anA);
    phaseC(posA, dpartA, seq0, t, 0);
    phaseB(arB, azB, anB, posB, HbB, dpartB, hB);
    bar_lgkm();   // HbB writes + dpartB + posA visible; Kloop_A reads retired
  }
  // epilogue: phaseC_B(29)
  phaseC(posB, dpartB, seq0 + NSEQ, 29, 64);
}

// ---- correction: out = pred + (goal - pred_T) * (t+1)/30, in place (verified) ----
__global__ void corr_k(float* __restrict__ out, const float* __restrict__ goals) {
  __shared__ float buf[240];
  int tid = threadIdx.x;
  int s0 = blockIdx.x * 4;
  float v = 0.f;
  if (tid < 240) { v = out[s0 * 60 + tid]; buf[tid] = v; }
  __syncthreads();
  if (tid < 240) {
    int sl = tid / 60;
    int rem = tid - sl * 60;
    int t = rem >> 1, c = rem & 1;
    float pT = buf[sl * 60 + 58 + c];
    float g = goals[(s0 + sl) * 2 + c];
    out[s0 * 60 + tid] = v + (g - pT) * ((float)(t + 1) * (1.f / 30.f));
  }
}

extern "C" void kernel_launch(void* const* d_in, const int* in_sizes, int n_in,
                              void* d_out, int out_size, void* d_ws, size_t ws_size,
                              hipStream_t stream) {
  (void)in_sizes; (void)n_in; (void)out_size; (void)ws_size;
  const float* ctx  = (const float*)d_in[0];
  const float* goals= (const float*)d_in[1];
  const float* emb  = (const float*)d_in[2];
  const float* Wh0  = (const float*)d_in[3];
  const float* bh0  = (const float*)d_in[4];
  const float* Wih  = (const float*)d_in[5];
  const float* Whh  = (const float*)d_in[6];
  const float* bih  = (const float*)d_in[7];
  const float* bhh  = (const float*)d_in[8];
  const float* Wout = (const float*)d_in[9];
  const float* bout = (const float*)d_in[10];
  float* out = (float*)d_out;

  unsigned short* Whhp3 = (unsigned short*)d_ws;                       // 393216 B
  unsigned short* Wh0p  = (unsigned short*)((char*)d_ws + 393216);     // 163840 B
  float* gpo = (float*)((char*)d_ws + 393216 + 163840);                // 12288 B

  hipLaunchKernelGGL(prep_whh3_k, dim3(768), dim3(256), 0, stream, Whh, Whhp3);
  hipLaunchKernelGGL(prep_wh0_k, dim3(320), dim3(256), 0, stream, Wh0, Wh0p);
  hipLaunchKernelGGL(prep_gp_k, dim3(1), dim3(256), 0, stream, bih, bhh, Wih, Wout, gpo);
  hipLaunchKernelGGL(gru_main_k, dim3(768), dim3(512), 0, stream,
                     ctx, goals, emb, bh0, bout, Wh0p, Whhp3, gpo, out);
  hipLaunchKernelGGL(corr_k, dim3(12288), dim3(256), 0, stream, out, goals);
}

// Round 3
// 2358.397 us; speedup vs baseline: 1.1427x; 1.1427x over previous
//
#include <hip/hip_runtime.h>

// TrajectoryDecoder r9: dual-chain pipelining, spill-free variant.
// r8 post-mortem: pipeline was CORRECT but h-in-regs pushed arch-VGPR past the
// 128/128 VGPR/AGPR split -> ~200 MB scratch writes -> scratch lines thrashed
// per-XCD L2 -> wR/wZ weight stream missed at 35% (FETCH 4.1 GB) -> kloops
// latency-bound (MfmaUtil 9%). Fix: h back to Hb/LDS (r6-verified), keeping the
// dual-chain interleave:
//   I1 = { Kloop_B(t) MFMA || phaseB_A(t) VALU || phaseC_B(t-1) } ; bar
//   I2 = { Kloop_A(t+1)    || phaseB_B(t)      || phaseC_A(t)   } ; bar
// Register budget: 96 acc (AGPR) + ~100 VGPR temps -> no spill -> L2 clean ->
// weight stream hits ~100% like r6 (r6: same stream volume, FETCH 7.7 MB).
// LDS 157,184 B; grid 768 (64 seqs/block), 1 block/CU, 8 waves.
// Verification metric: WRITE_SIZE must return to ~12 MB (out only).

typedef __attribute__((ext_vector_type(8))) short short8;
typedef __bf16 bf16x8 __attribute__((ext_vector_type(8)));
typedef float f32x16 __attribute__((ext_vector_type(16)));
typedef float f32x4 __attribute__((ext_vector_type(4)));

#define HSTR 264               // Hb stride (bf16): 528B rows; balanced banks
#define NSEQ 32                // seqs per chain (2 chains per block)
#define WNL_SLICES 14          // wN k-slices staged in LDS (ks 14,15 from L2)
#define WHH3_ELEMS (24 * 16 * 64 * 8)  // 196608 = 768x256
#define WH0_ELEMS (8 * 20 * 64 * 8)    // 81920

static __device__ __forceinline__ unsigned short f2bf(float f) {
  unsigned u = __builtin_bit_cast(unsigned, f);
  u += 0x7fffu + ((u >> 16) & 1u);   // RNE
  return (unsigned short)(u >> 16);
}
static __device__ __forceinline__ float bf2f(unsigned short h) {
  unsigned u = ((unsigned)h) << 16;
  return __builtin_bit_cast(float, u);
}
static __device__ __forceinline__ bf16x8 ldfrag(const unsigned short* p) {
  return __builtin_bit_cast(bf16x8, *(const short8*)p);
}
static __device__ __forceinline__ float fsig(float x) {
  return __builtin_amdgcn_rcpf(1.f + __builtin_amdgcn_exp2f(-1.44269504f * x));
}
static __device__ __forceinline__ float ftanh(float x) {
  return 1.f - 2.f * __builtin_amdgcn_rcpf(1.f + __builtin_amdgcn_exp2f(2.88539008f * x));
}
static __device__ __forceinline__ float dpp16sum(float x) {
  x += __builtin_bit_cast(float, __builtin_amdgcn_update_dpp(0, __builtin_bit_cast(int, x), 0xB1, 0xF, 0xF, true));
  x += __builtin_bit_cast(float, __builtin_amdgcn_update_dpp(0, __builtin_bit_cast(int, x), 0x4E, 0xF, 0xF, true));
  x += __builtin_bit_cast(float, __builtin_amdgcn_update_dpp(0, __builtin_bit_cast(int, x), 0x141, 0xF, 0xF, true));
  x += __builtin_bit_cast(float, __builtin_amdgcn_update_dpp(0, __builtin_bit_cast(int, x), 0x140, 0xF, 0xF, true));
  return x;
}
// LDS-only barrier (r4-verified): no vmcnt drain; t-loop vmem = weight loads
// (compiler-waited before MFMA use) + out stores (fire-and-forget).
static __device__ __forceinline__ void bar_lgkm() {
  asm volatile("s_waitcnt lgkmcnt(0)\n\ts_barrier" ::: "memory");
}

// ---- prep: pack W_hh slice-major: [(g*8+w)*16 + ks][lane][8]  (r3-verified) ----
__global__ void prep_whh3_k(const float* __restrict__ Whh, unsigned short* __restrict__ Whhp3) {
  int i = blockIdx.x * 256 + threadIdx.x;
  if (i >= WHH3_ELEMS) return;
  int j = i & 7;
  int lane = (i >> 3) & 63;
  int rest = i >> 9;
  int ks = rest & 15;
  int sw = rest >> 4;
  int g = sw >> 3, w = sw & 7;
  int row = g * 256 + w * 32 + (lane & 31);
  int k = ks * 16 + ((lane >> 5) << 3) + j;
  Whhp3[i] = f2bf(Whh[row * 256 + k]);
}

// ---- prep: pack W_h0 (256 x 290, K padded to 320)  (r3-verified) ----
__global__ void prep_wh0_k(const float* __restrict__ Wh0, unsigned short* __restrict__ Wh0p) {
  int i = blockIdx.x * 256 + threadIdx.x;
  if (i >= WH0_ELEMS) return;
  int j = i & 7;
  int lane = (i >> 3) & 63;
  int rest = i >> 9;
  int ks = rest % 20;
  int nt = rest / 20;
  int row = nt * 32 + (lane & 31);
  int k = ks * 16 + ((lane >> 5) << 3) + j;
  float v = (k < 290) ? Wh0[row * 290 + k] : 0.f;
  Wh0p[i] = f2bf(v);
}

// ---- prep: per-h-unit params (r3-verified) ----
__global__ void prep_gp_k(const float* __restrict__ bih, const float* __restrict__ bhh,
                          const float* __restrict__ Wih, const float* __restrict__ Wout,
                          float* __restrict__ gpo) {
  int n = threadIdx.x;
  gpo[n * 12 + 0]  = bih[n] + bhh[n];
  gpo[n * 12 + 1]  = bih[n + 256] + bhh[n + 256];
  gpo[n * 12 + 2]  = bih[n + 512];
  gpo[n * 12 + 3]  = bhh[n + 512];
  gpo[n * 12 + 4]  = Wih[n * 2 + 0];
  gpo[n * 12 + 5]  = Wih[n * 2 + 1];
  gpo[n * 12 + 6]  = Wih[(n + 256) * 2 + 0];
  gpo[n * 12 + 7]  = Wih[(n + 256) * 2 + 1];
  gpo[n * 12 + 8]  = Wih[(n + 512) * 2 + 0];
  gpo[n * 12 + 9]  = Wih[(n + 512) * 2 + 1];
  gpo[n * 12 + 10] = Wout[n];
  gpo[n * 12 + 11] = Wout[256 + n];
}

// ---------------- main fused GRU, dual-chain pipelined ----------------
__global__ __launch_bounds__(512, 2) void gru_main_k(
    const float* __restrict__ ctx, const float* __restrict__ goals,
    const float* __restrict__ emb, const float* __restrict__ bh0,
    const float* __restrict__ bout,
    const unsigned short* __restrict__ Wh0p,
    const unsigned short* __restrict__ Whhp3,
    const float* __restrict__ gp,
    float* __restrict__ out) {
  __shared__ __align__(16) unsigned short wNl[8 * WNL_SLICES * 64 * 8]; // 114688 B
  __shared__ __align__(16) unsigned short HbA[NSEQ * HSTR];            // 16896 B
  __shared__ __align__(16) unsigned short HbB[NSEQ * HSTR];            // 16896 B
  __shared__ __align__(16) float dpartA[16 * NSEQ * 2];                // 4096 B
  __shared__ __align__(16) float dpartB[16 * NSEQ * 2];                // 4096 B
  __shared__ __align__(16) float posA[NSEQ * 2];                       // 256 B
  __shared__ __align__(16) float posB[NSEQ * 2];                       // 256 B
  // total 157,184 B <= 160 KiB; 1 block/CU, 8 waves (2/SIMD)

  const int tid = threadIdx.x;
  const int w = tid >> 6;
  const int l = tid & 63;
  const int l31 = l & 31;
  const int grp = l >> 5;
  const int seq0 = blockIdx.x * (2 * NSEQ);
  const int n0 = w * 32 + l31;

  // ---- stage wN slices 0..13 per wave into LDS, block-cooperative ----
  {
    short8* wdst = (short8*)wNl;
    const short8* wsrc = (const short8*)Whhp3;
    for (int f = tid; f < 8 * WNL_SLICES * 64; f += 512) {
      int ll = f & 63;
      int t2 = f >> 6;
      int ks = t2 % WNL_SLICES;
      int ww = t2 / WNL_SLICES;
      wdst[f] = wsrc[((16 + ww) * 16 + ks) * 64 + ll];   // g=2 region
    }
  }

  // ---------------- Phase 0: h0 = init_in @ W_h0^T + b_h0 (per chain) ----------------
  auto phase0 = [&](unsigned short* Hb, int sBase, f32x16& acc0) {
    acc0 = f32x16{};
    unsigned short* As = Hb;   // overlay staging, stride 176 (5632 shorts < 8448)
    for (int cc = 0; cc < 2; ++cc) {
      for (int i = tid; i < NSEQ * 160; i += 512) {
        int row = i / 160;
        int col = i - row * 160;
        int d = cc * 160 + col;
        int s = sBase + row;
        int b = s / 6;
        float v;
        if (d < 256)      v = ctx[b * 256 + d];
        else if (d < 258) v = goals[s * 2 + (d - 256)];
        else if (d < 290) v = emb[b * 32 + (d - 258)];
        else              v = 0.f;
        As[row * 176 + col] = f2bf(v);
      }
      __syncthreads();   // also orders wNl staging (first pass)
      for (int ks = 0; ks < 10; ++ks) {
        bf16x8 bf = ldfrag(&Wh0p[((w * 20 + cc * 10 + ks) * 64 + l) * 8]);
        bf16x8 af = ldfrag(&As[l31 * 176 + ks * 16 + grp * 8]);
        acc0 = __builtin_amdgcn_mfma_f32_32x32x16_bf16(af, bf, acc0, 0, 0, 0);
      }
      __syncthreads();
    }
    // write h0 into Hb (C/D layout [m74/m101]); readers sync before t-loop
    float b0 = bh0[n0];
#pragma unroll
    for (int r = 0; r < 16; ++r) {
      int row = (r & 3) + 8 * (r >> 2) + 4 * grp;
      Hb[row * HSTR + n0] = f2bf(acc0[r] + b0);
    }
  };

  {
    f32x16 acc0;
    phase0(HbA, seq0, acc0);
    phase0(HbB, seq0 + NSEQ, acc0);
  }
  if (tid < 2 * NSEQ) { posA[tid] = 0.f; posB[tid] = 0.f; }

  float brr, bzz, bin_, bhn, wr0, wr1, wz0, wz1, wn0, wn1, wo0, wo1;
  {
    f32x4 g0 = *(const f32x4*)&gp[n0 * 12];
    f32x4 g1 = *(const f32x4*)&gp[n0 * 12 + 4];
    f32x4 g2 = *(const f32x4*)&gp[n0 * 12 + 8];
    brr = g0[0]; bzz = g0[1]; bin_ = g0[2]; bhn = g0[3];
    wr0 = g1[0]; wr1 = g1[1]; wz0 = g1[2]; wz1 = g1[3];
    wn0 = g2[0]; wn1 = g2[1]; wo0 = g2[2]; wo1 = g2[3];
  }
  const float bo0 = bout[0], bo1 = bout[1];
  __syncthreads();   // h0 writes + pos init visible to all

  // Per-wave weight-stream base pointers (L2-resident, 393 KB set)
  const unsigned short* wRb = &Whhp3[((w * 16) * 64 + l) * 8];          // g=0
  const unsigned short* wZb = &Whhp3[(((8 + w) * 16) * 64 + l) * 8];    // g=1
  const unsigned short* wNg = &Whhp3[(((16 + w) * 16) * 64 + l) * 8];   // g=2

  // K-loop: A from Hb (LDS), wR/wZ streamed from L2, wN from LDS (+2 slices L2)
  auto kloop = [&](const unsigned short* Hb, f32x16& ar, f32x16& az, f32x16& an) {
    ar = f32x16{}; az = f32x16{}; an = f32x16{};
#pragma unroll
    for (int ks = 0; ks < 16; ++ks) {
      bf16x8 af = ldfrag(&Hb[l31 * HSTR + ks * 16 + grp * 8]);
      bf16x8 bR = ldfrag(&wRb[ks * 512]);
      bf16x8 bZ = ldfrag(&wZb[ks * 512]);
      bf16x8 bN = (ks < WNL_SLICES)
          ? ldfrag(&wNl[((w * WNL_SLICES + ks) * 64 + l) * 8])
          : ldfrag(&wNg[ks * 512]);
      ar = __builtin_amdgcn_mfma_f32_32x32x16_bf16(af, bR, ar, 0, 0, 0);
      az = __builtin_amdgcn_mfma_f32_32x32x16_bf16(af, bZ, az, 0, 0, 0);
      an = __builtin_amdgcn_mfma_f32_32x32x16_bf16(af, bN, an, 0, 0, 0);
    }
  };

  // Phase B: gates + h update (h via Hb/LDS, r6-verified) + delta partials
  auto phaseB = [&](const f32x16& ar, const f32x16& az, const f32x16& an,
                    float* posL, unsigned short* Hb, float* dpart) {
#pragma unroll
    for (int q2 = 0; q2 < 4; ++q2) {
      int sb = 8 * q2 + 4 * grp;
      f32x4 xyA = *(const f32x4*)&posL[sb * 2];
      f32x4 xyB = *(const f32x4*)&posL[sb * 2 + 4];
#pragma unroll
      for (int e = 0; e < 4; ++e) {
        int r = 4 * q2 + e;
        int s = sb + e;
        float x = (e == 0) ? xyA[0] : (e == 1) ? xyA[2] : (e == 2) ? xyB[0] : xyB[2];
        float y = (e == 0) ? xyA[1] : (e == 1) ? xyA[3] : (e == 2) ? xyB[1] : xyB[3];
        int ha = s * HSTR + n0;
        float h = bf2f(Hb[ha]);
        float rg = fsig(ar[r] + brr + x * wr0 + y * wr1);
        float zg = fsig(az[r] + bzz + x * wz0 + y * wz1);
        float ng = ftanh(fmaf(rg, an[r] + bhn, fmaf(x, wn0, fmaf(y, wn1, bin_))));
        float hnew = fmaf(zg, h - ng, ng);     // (1-z)*n + z*h
        Hb[ha] = f2bf(hnew);
        float dx = dpp16sum(hnew * wo0);
        float dy = dpp16sum(hnew * wo1);
        if ((l & 15) == 0) {
          int p16 = w * 2 + ((l >> 4) & 1);
          dpart[(p16 * NSEQ + s) * 2]     = dx;
          dpart[(p16 * NSEQ + s) * 2 + 1] = dy;
        }
      }
    }
  };

  // Phase C (one wave per chain): pos update + raw pred store
  auto phaseC = [&](float* posL, float* dpart, int sBase, int st, int tbase) {
    int tt = tid - tbase;
    if (tt >= 0 && tt < 2 * NSEQ) {
      int s = tt >> 1, c = tt & 1;
      float d = (c == 0) ? bo0 : bo1;
#pragma unroll
      for (int q = 0; q < 16; ++q) d += dpart[(q * NSEQ + s) * 2 + c];
      float p = posL[tt] + d;
      posL[tt] = p;
      out[((sBase + s) * 30 + st) * 2 + c] = p;
    }
  };

  // ---------------- T recurrent steps, dual-chain pipelined ----------------
  f32x16 arA, azA, anA, arB, azB, anB;
  kloop(HbA, arA, azA, anA);              // Kloop_A(0)

#pragma unroll 1
  for (int t = 0; t < 30; ++t) {
    // I1: Kloop_B(t) MFMA || phaseC_B(t-1) || phaseB_A(t) VALU
    kloop(HbB, arB, azB, anB);
    if (t > 0) phaseC(posB, dpartB, seq0 + NSEQ, t - 1, 64);
    phaseB(arA, azA, anA, posA, HbA, dpartA);
    bar_lgkm();   // HbA writes + dpartA visible; Kloop_B reads of HbB retired
    // I2: Kloop_A(t+1) MFMA || phaseC_A(t) || phaseB_B(t) VALU
    if (t < 29) kloop(HbA, arA, azA, anA);
    phaseC(posA, dpartA, seq0, t, 0);
    phaseB(arB, azB, anB, posB, HbB, dpartB);
    bar_lgkm();   // HbB writes + dpartB + posA visible; Kloop_A reads retired
  }
  // epilogue: phaseC_B(29)
  phaseC(posB, dpartB, seq0 + NSEQ, 29, 64);
}

// ---- correction: out = pred + (goal - pred_T) * (t+1)/30, in place (verified) ----
__global__ void corr_k(float* __restrict__ out, const float* __restrict__ goals) {
  __shared__ float buf[240];
  int tid = threadIdx.x;
  int s0 = blockIdx.x * 4;
  float v = 0.f;
  if (tid < 240) { v = out[s0 * 60 + tid]; buf[tid] = v; }
  __syncthreads();
  if (tid < 240) {
    int sl = tid / 60;
    int rem = tid - sl * 60;
    int t = rem >> 1, c = rem & 1;
    float pT = buf[sl * 60 + 58 + c];
    float g = goals[(s0 + sl) * 2 + c];
    out[s0 * 60 + tid] = v + (g - pT) * ((float)(t + 1) * (1.f / 30.f));
  }
}

extern "C" void kernel_launch(void* const* d_in, const int* in_sizes, int n_in,
                              void* d_out, int out_size, void* d_ws, size_t ws_size,
                              hipStream_t stream) {
  (void)in_sizes; (void)n_in; (void)out_size; (void)ws_size;
  const float* ctx  = (const float*)d_in[0];
  const float* goals= (const float*)d_in[1];
  const float* emb  = (const float*)d_in[2];
  const float* Wh0  = (const float*)d_in[3];
  const float* bh0  = (const float*)d_in[4];
  const float* Wih  = (const float*)d_in[5];
  const float* Whh  = (const float*)d_in[6];
  const float* bih  = (const float*)d_in[7];
  const float* bhh  = (const float*)d_in[8];
  const float* Wout = (const float*)d_in[9];
  const float* bout = (const float*)d_in[10];
  float* out = (float*)d_out;

  unsigned short* Whhp3 = (unsigned short*)d_ws;                       // 393216 B
  unsigned short* Wh0p  = (unsigned short*)((char*)d_ws + 393216);     // 163840 B
  float* gpo = (float*)((char*)d_ws + 393216 + 163840);                // 12288 B

  hipLaunchKernelGGL(prep_whh3_k, dim3(768), dim3(256), 0, stream, Whh, Whhp3);
  hipLaunchKernelGGL(prep_wh0_k, dim3(320), dim3(256), 0, stream, Wh0, Wh0p);
  hipLaunchKernelGGL(prep_gp_k, dim3(1), dim3(256), 0, stream, bih, bhh, Wih, Wout, gpo);
  hipLaunchKernelGGL(gru_main_k, dim3(768), dim3(512), 0, stream,
                     ctx, goals, emb, bh0, bout, Wh0p, Whhp3, gpo, out);
  hipLaunchKernelGGL(corr_k, dim3(12288), dim3(256), 0, stream, out, goals);
}

// Round 6
// 1201.573 us; speedup vs baseline: 2.2428x; 1.9628x over previous
//
#include <hip/hip_runtime.h>

// TrajectoryDecoder r12 = r9 (PASSING dual-chain) + bounded-hoist kloop.
// r10/r11 post-mortem: stacked mechanisms (gload_lds ring + inline-asm "+a"
// MFMA + wave-order split + posH flush) failed at absmax ~0.39 twice and the
// WAR-fence fix changed nothing -> un-attributable; retreat to r9 (passed,
// absmax 0.031) and change ONE thing.
// r9's spill re-diagnosis: fully-unrolled kloop let the scheduler hoist all 32
// global weight loads (128 VGPRs in flight) + 96 acc + temps = ~264 > 256-reg
// budget -> spill -> scratch thrashed L2 -> stream missed (FETCH 2.7 GB).
// Fix: #pragma unroll 4 on the ks-loop caps in-flight loads at 16 (64 VGPRs):
// 96 acc + 64 + ~40 temps = 200 <= 256 -> spill-free. The exposed per-group
// L2 latency hides under the SIMD-mate waves' phaseB (dual-chain design):
//   I1 = { Kloop_B(t) MFMA || phaseB_A(t) VALU || phaseC_B(t-1) } ; bar
//   I2 = { Kloop_A(t+1)    || phaseB_B(t)      || phaseC_A(t)   } ; bar
// Verification metrics: WRITE_SIZE ~12 MB (spill gone), FETCH < 100 MB.
// LDS 157,184 B; grid 768 (64 seqs/block), 1 block/CU, 8 waves (2/SIMD).

typedef __attribute__((ext_vector_type(8))) short short8;
typedef __bf16 bf16x8 __attribute__((ext_vector_type(8)));
typedef float f32x16 __attribute__((ext_vector_type(16)));
typedef float f32x4 __attribute__((ext_vector_type(4)));

#define HSTR 264               // Hb stride (bf16): 528B rows; balanced banks
#define NSEQ 32                // seqs per chain (2 chains per block)
#define WNL_SLICES 14          // wN k-slices staged in LDS (ks 14,15 from L2)
#define WHH3_ELEMS (24 * 16 * 64 * 8)  // 196608 = 768x256
#define WH0_ELEMS (8 * 20 * 64 * 8)    // 81920

static __device__ __forceinline__ unsigned short f2bf(float f) {
  unsigned u = __builtin_bit_cast(unsigned, f);
  u += 0x7fffu + ((u >> 16) & 1u);   // RNE
  return (unsigned short)(u >> 16);
}
static __device__ __forceinline__ float bf2f(unsigned short h) {
  unsigned u = ((unsigned)h) << 16;
  return __builtin_bit_cast(float, u);
}
static __device__ __forceinline__ bf16x8 ldfrag(const unsigned short* p) {
  return __builtin_bit_cast(bf16x8, *(const short8*)p);
}
static __device__ __forceinline__ float fsig(float x) {
  return __builtin_amdgcn_rcpf(1.f + __builtin_amdgcn_exp2f(-1.44269504f * x));
}
static __device__ __forceinline__ float ftanh(float x) {
  return 1.f - 2.f * __builtin_amdgcn_rcpf(1.f + __builtin_amdgcn_exp2f(2.88539008f * x));
}
static __device__ __forceinline__ float dpp16sum(float x) {
  x += __builtin_bit_cast(float, __builtin_amdgcn_update_dpp(0, __builtin_bit_cast(int, x), 0xB1, 0xF, 0xF, true));
  x += __builtin_bit_cast(float, __builtin_amdgcn_update_dpp(0, __builtin_bit_cast(int, x), 0x4E, 0xF, 0xF, true));
  x += __builtin_bit_cast(float, __builtin_amdgcn_update_dpp(0, __builtin_bit_cast(int, x), 0x141, 0xF, 0xF, true));
  x += __builtin_bit_cast(float, __builtin_amdgcn_update_dpp(0, __builtin_bit_cast(int, x), 0x140, 0xF, 0xF, true));
  return x;
}
// LDS-only barrier (r4-verified): no vmcnt drain; t-loop vmem = weight loads
// (compiler-waited before MFMA use) + out stores (fire-and-forget).
static __device__ __forceinline__ void bar_lgkm() {
  asm volatile("s_waitcnt lgkmcnt(0)\n\ts_barrier" ::: "memory");
}

// ---- prep: pack W_hh slice-major: [(g*8+w)*16 + ks][lane][8]  (r3-verified) ----
__global__ void prep_whh3_k(const float* __restrict__ Whh, unsigned short* __restrict__ Whhp3) {
  int i = blockIdx.x * 256 + threadIdx.x;
  if (i >= WHH3_ELEMS) return;
  int j = i & 7;
  int lane = (i >> 3) & 63;
  int rest = i >> 9;
  int ks = rest & 15;
  int sw = rest >> 4;
  int g = sw >> 3, w = sw & 7;
  int row = g * 256 + w * 32 + (lane & 31);
  int k = ks * 16 + ((lane >> 5) << 3) + j;
  Whhp3[i] = f2bf(Whh[row * 256 + k]);
}

// ---- prep: pack W_h0 (256 x 290, K padded to 320)  (r3-verified) ----
__global__ void prep_wh0_k(const float* __restrict__ Wh0, unsigned short* __restrict__ Wh0p) {
  int i = blockIdx.x * 256 + threadIdx.x;
  if (i >= WH0_ELEMS) return;
  int j = i & 7;
  int lane = (i >> 3) & 63;
  int rest = i >> 9;
  int ks = rest % 20;
  int nt = rest / 20;
  int row = nt * 32 + (lane & 31);
  int k = ks * 16 + ((lane >> 5) << 3) + j;
  float v = (k < 290) ? Wh0[row * 290 + k] : 0.f;
  Wh0p[i] = f2bf(v);
}

// ---- prep: per-h-unit params (r3-verified) ----
__global__ void prep_gp_k(const float* __restrict__ bih, const float* __restrict__ bhh,
                          const float* __restrict__ Wih, const float* __restrict__ Wout,
                          float* __restrict__ gpo) {
  int n = threadIdx.x;
  gpo[n * 12 + 0]  = bih[n] + bhh[n];
  gpo[n * 12 + 1]  = bih[n + 256] + bhh[n + 256];
  gpo[n * 12 + 2]  = bih[n + 512];
  gpo[n * 12 + 3]  = bhh[n + 512];
  gpo[n * 12 + 4]  = Wih[n * 2 + 0];
  gpo[n * 12 + 5]  = Wih[n * 2 + 1];
  gpo[n * 12 + 6]  = Wih[(n + 256) * 2 + 0];
  gpo[n * 12 + 7]  = Wih[(n + 256) * 2 + 1];
  gpo[n * 12 + 8]  = Wih[(n + 512) * 2 + 0];
  gpo[n * 12 + 9]  = Wih[(n + 512) * 2 + 1];
  gpo[n * 12 + 10] = Wout[n];
  gpo[n * 12 + 11] = Wout[256 + n];
}

// ---------------- main fused GRU, dual-chain pipelined ----------------
__global__ __launch_bounds__(512, 2) void gru_main_k(
    const float* __restrict__ ctx, const float* __restrict__ goals,
    const float* __restrict__ emb, const float* __restrict__ bh0,
    const float* __restrict__ bout,
    const unsigned short* __restrict__ Wh0p,
    const unsigned short* __restrict__ Whhp3,
    const float* __restrict__ gp,
    float* __restrict__ out) {
  __shared__ __align__(16) unsigned short wNl[8 * WNL_SLICES * 64 * 8]; // 114688 B
  __shared__ __align__(16) unsigned short HbA[NSEQ * HSTR];            // 16896 B
  __shared__ __align__(16) unsigned short HbB[NSEQ * HSTR];            // 16896 B
  __shared__ __align__(16) float dpartA[16 * NSEQ * 2];                // 4096 B
  __shared__ __align__(16) float dpartB[16 * NSEQ * 2];                // 4096 B
  __shared__ __align__(16) float posA[NSEQ * 2];                       // 256 B
  __shared__ __align__(16) float posB[NSEQ * 2];                       // 256 B
  // total 157,184 B <= 160 KiB; 1 block/CU, 8 waves (2/SIMD)

  const int tid = threadIdx.x;
  const int w = tid >> 6;
  const int l = tid & 63;
  const int l31 = l & 31;
  const int grp = l >> 5;
  const int seq0 = blockIdx.x * (2 * NSEQ);
  const int n0 = w * 32 + l31;

  // ---- stage wN slices 0..13 per wave into LDS, block-cooperative ----
  {
    short8* wdst = (short8*)wNl;
    const short8* wsrc = (const short8*)Whhp3;
    for (int f = tid; f < 8 * WNL_SLICES * 64; f += 512) {
      int ll = f & 63;
      int t2 = f >> 6;
      int ks = t2 % WNL_SLICES;
      int ww = t2 / WNL_SLICES;
      wdst[f] = wsrc[((16 + ww) * 16 + ks) * 64 + ll];   // g=2 region
    }
  }

  // ---------------- Phase 0: h0 = init_in @ W_h0^T + b_h0 (per chain) ----------------
  auto phase0 = [&](unsigned short* Hb, int sBase) {
    f32x16 acc0 = f32x16{};
    unsigned short* As = Hb;   // overlay staging, stride 176 (5632 shorts < 8448)
    for (int cc = 0; cc < 2; ++cc) {
      for (int i = tid; i < NSEQ * 160; i += 512) {
        int row = i / 160;
        int col = i - row * 160;
        int d = cc * 160 + col;
        int s = sBase + row;
        int b = s / 6;
        float v;
        if (d < 256)      v = ctx[b * 256 + d];
        else if (d < 258) v = goals[s * 2 + (d - 256)];
        else if (d < 290) v = emb[b * 32 + (d - 258)];
        else              v = 0.f;
        As[row * 176 + col] = f2bf(v);
      }
      __syncthreads();   // also orders the wNl staging writes (first pass)
      for (int ks = 0; ks < 10; ++ks) {
        bf16x8 bf = ldfrag(&Wh0p[((w * 20 + cc * 10 + ks) * 64 + l) * 8]);
        bf16x8 af = ldfrag(&As[l31 * 176 + ks * 16 + grp * 8]);
        acc0 = __builtin_amdgcn_mfma_f32_32x32x16_bf16(af, bf, acc0, 0, 0, 0);
      }
      __syncthreads();
    }
    // write h0 into Hb (C/D layout [m74/m101]); readers sync before t-loop
    float b0 = bh0[n0];
#pragma unroll
    for (int r = 0; r < 16; ++r) {
      int row = (r & 3) + 8 * (r >> 2) + 4 * grp;
      Hb[row * HSTR + n0] = f2bf(acc0[r] + b0);
    }
  };

  phase0(HbA, seq0);
  phase0(HbB, seq0 + NSEQ);
  if (tid < 2 * NSEQ) { posA[tid] = 0.f; posB[tid] = 0.f; }

  float brr, bzz, bin_, bhn, wr0, wr1, wz0, wz1, wn0, wn1, wo0, wo1;
  {
    f32x4 g0 = *(const f32x4*)&gp[n0 * 12];
    f32x4 g1 = *(const f32x4*)&gp[n0 * 12 + 4];
    f32x4 g2 = *(const f32x4*)&gp[n0 * 12 + 8];
    brr = g0[0]; bzz = g0[1]; bin_ = g0[2]; bhn = g0[3];
    wr0 = g1[0]; wr1 = g1[1]; wz0 = g1[2]; wz1 = g1[3];
    wn0 = g2[0]; wn1 = g2[1]; wo0 = g2[2]; wo1 = g2[3];
  }
  const float bo0 = bout[0], bo1 = bout[1];
  __syncthreads();   // h0 writes + pos init visible to all

  // Per-wave weight-stream base pointers (L2-resident, 393 KB set)
  const unsigned short* wRb = &Whhp3[((w * 16) * 64 + l) * 8];          // g=0
  const unsigned short* wZb = &Whhp3[(((8 + w) * 16) * 64 + l) * 8];    // g=1
  const unsigned short* wNg = &Whhp3[(((16 + w) * 16) * 64 + l) * 8];   // g=2

  // K-loop: A from Hb (LDS), wR/wZ streamed from L2, wN from LDS (+2 slices L2).
  // unroll 4 (NOT full): bounds scheduler load-hoisting to 16 loads (64 VGPRs)
  // -> total reg demand ~200 <= 256 -> no spill (r9's failure mechanism).
  auto kloop = [&](const unsigned short* Hb, f32x16& ar, f32x16& az, f32x16& an) {
    ar = f32x16{}; az = f32x16{}; an = f32x16{};
#pragma unroll 4
    for (int ks = 0; ks < 16; ++ks) {
      bf16x8 af = ldfrag(&Hb[l31 * HSTR + ks * 16 + grp * 8]);
      bf16x8 bR = ldfrag(&wRb[ks * 512]);
      bf16x8 bZ = ldfrag(&wZb[ks * 512]);
      bf16x8 bN = (ks < WNL_SLICES)
          ? ldfrag(&wNl[((w * WNL_SLICES + ks) * 64 + l) * 8])
          : ldfrag(&wNg[ks * 512]);
      ar = __builtin_amdgcn_mfma_f32_32x32x16_bf16(af, bR, ar, 0, 0, 0);
      az = __builtin_amdgcn_mfma_f32_32x32x16_bf16(af, bZ, az, 0, 0, 0);
      an = __builtin_amdgcn_mfma_f32_32x32x16_bf16(af, bN, an, 0, 0, 0);
    }
  };

  // Phase B: gates + h update (h via Hb/LDS, r6-verified) + delta partials
  auto phaseB = [&](const f32x16& ar, const f32x16& az, const f32x16& an,
                    float* posL, unsigned short* Hb, float* dpart) {
#pragma unroll
    for (int q2 = 0; q2 < 4; ++q2) {
      int sb = 8 * q2 + 4 * grp;
      f32x4 xyA = *(const f32x4*)&posL[sb * 2];
      f32x4 xyB = *(const f32x4*)&posL[sb * 2 + 4];
#pragma unroll
      for (int e = 0; e < 4; ++e) {
        int r = 4 * q2 + e;
        int s = sb + e;
        float x = (e == 0) ? xyA[0] : (e == 1) ? xyA[2] : (e == 2) ? xyB[0] : xyB[2];
        float y = (e == 0) ? xyA[1] : (e == 1) ? xyA[3] : (e == 2) ? xyB[1] : xyB[3];
        int ha = s * HSTR + n0;
        float h = bf2f(Hb[ha]);
        float rg = fsig(ar[r] + brr + x * wr0 + y * wr1);
        float zg = fsig(az[r] + bzz + x * wz0 + y * wz1);
        float ng = ftanh(fmaf(rg, an[r] + bhn, fmaf(x, wn0, fmaf(y, wn1, bin_))));
        float hnew = fmaf(zg, h - ng, ng);     // (1-z)*n + z*h
        Hb[ha] = f2bf(hnew);
        float dx = dpp16sum(hnew * wo0);
        float dy = dpp16sum(hnew * wo1);
        if ((l & 15) == 0) {
          int p16 = w * 2 + ((l >> 4) & 1);
          dpart[(p16 * NSEQ + s) * 2]     = dx;
          dpart[(p16 * NSEQ + s) * 2 + 1] = dy;
        }
      }
    }
  };

  // Phase C (one wave per chain): pos update + raw pred store
  auto phaseC = [&](float* posL, float* dpart, int sBase, int st, int tbase) {
    int tt = tid - tbase;
    if (tt >= 0 && tt < 2 * NSEQ) {
      int s = tt >> 1, c = tt & 1;
      float d = (c == 0) ? bo0 : bo1;
#pragma unroll
      for (int q = 0; q < 16; ++q) d += dpart[(q * NSEQ + s) * 2 + c];
      float p = posL[tt] + d;
      posL[tt] = p;
      out[((sBase + s) * 30 + st) * 2 + c] = p;
    }
  };

  // ---------------- T recurrent steps, dual-chain pipelined ----------------
  f32x16 arA, azA, anA, arB, azB, anB;
  kloop(HbA, arA, azA, anA);              // Kloop_A(0)

#pragma unroll 1
  for (int t = 0; t < 30; ++t) {
    // I1: Kloop_B(t) || phaseC_B(t-1) || phaseB_A(t)
    kloop(HbB, arB, azB, anB);
    if (t > 0) phaseC(posB, dpartB, seq0 + NSEQ, t - 1, 64);
    phaseB(arA, azA, anA, posA, HbA, dpartA);
    bar_lgkm();   // HbA writes + dpartA visible; Kloop_B reads of HbB retired
    // I2: Kloop_A(t+1) || phaseC_A(t) || phaseB_B(t)
    if (t < 29) kloop(HbA, arA, azA, anA);
    phaseC(posA, dpartA, seq0, t, 0);
    phaseB(arB, azB, anB, posB, HbB, dpartB);
    bar_lgkm();   // HbB writes + dpartB + posA visible; Kloop_A reads retired
  }
  // epilogue: phaseC_B(29)
  phaseC(posB, dpartB, seq0 + NSEQ, 29, 64);
}

// ---- correction: out = pred + (goal - pred_T) * (t+1)/30, in place (verified) ----
__global__ void corr_k(float* __restrict__ out, const float* __restrict__ goals) {
  __shared__ float buf[240];
  int tid = threadIdx.x;
  int s0 = blockIdx.x * 4;
  float v = 0.f;
  if (tid < 240) { v = out[s0 * 60 + tid]; buf[tid] = v; }
  __syncthreads();
  if (tid < 240) {
    int sl = tid / 60;
    int rem = tid - sl * 60;
    int t = rem >> 1, c = rem & 1;
    float pT = buf[sl * 60 + 58 + c];
    float g = goals[(s0 + sl) * 2 + c];
    out[s0 * 60 + tid] = v + (g - pT) * ((float)(t + 1) * (1.f / 30.f));
  }
}

extern "C" void kernel_launch(void* const* d_in, const int* in_sizes, int n_in,
                              void* d_out, int out_size, void* d_ws, size_t ws_size,
                              hipStream_t stream) {
  (void)in_sizes; (void)n_in; (void)out_size; (void)ws_size;
  const float* ctx  = (const float*)d_in[0];
  const float* goals= (const float*)d_in[1];
  const float* emb  = (const float*)d_in[2];
  const float* Wh0  = (const float*)d_in[3];
  const float* bh0  = (const float*)d_in[4];
  const float* Wih  = (const float*)d_in[5];
  const float* Whh  = (const float*)d_in[6];
  const float* bih  = (const float*)d_in[7];
  const float* bhh  = (const float*)d_in[8];
  const float* Wout = (const float*)d_in[9];
  const float* bout = (const float*)d_in[10];
  float* out = (float*)d_out;

  unsigned short* Whhp3 = (unsigned short*)d_ws;                       // 393216 B
  unsigned short* Wh0p  = (unsigned short*)((char*)d_ws + 393216);     // 163840 B
  float* gpo = (float*)((char*)d_ws + 393216 + 163840);                // 12288 B

  hipLaunchKernelGGL(prep_whh3_k, dim3(768), dim3(256), 0, stream, Whh, Whhp3);
  hipLaunchKernelGGL(prep_wh0_k, dim3(320), dim3(256), 0, stream, Wh0, Wh0p);
  hipLaunchKernelGGL(prep_gp_k, dim3(1), dim3(256), 0, stream, bih, bhh, Wih, Wout, gpo);
  hipLaunchKernelGGL(gru_main_k, dim3(768), dim3(512), 0, stream,
                     ctx, goals, emb, bh0, bout, Wh0p, Whhp3, gpo, out);
  hipLaunchKernelGGL(corr_k, dim3(12288), dim3(256), 0, stream, out, goals);
}

// Round 7
// 1165.846 us; speedup vs baseline: 2.3115x; 1.0306x over previous
//
#include <hip/hip_runtime.h>

// TrajectoryDecoder r13 = r12 (PASSING, spill-free dual-chain) + wave-order split.
// r12 post-mortem: spill fixed (WRITE 11.5 MB, VGPR 108) but NO overlap:
// MfmaUtil 20.5 + VALUBusy 50, dur 1201 (worse than r6's 985). Cause: kloop_B
// and phaseB_A were in the SAME wave's program order; compiler kept them as
// sequential clusters, and barriers keep all 8 waves in the same phase -> both
// SIMD waves do MFMA together then VALU together (lockstep, like r6).
// Fix (the ONE change): wave-order split. Waves 0-3: kloop -> phaseB.
// Waves 4-7: phaseB -> kloop. SIMD i hosts waves i and i+4, so each SIMD
// always has one MFMA-issuing and one VALU-issuing wave; HW co-issues
// (m114: separate pipes, time = max not sum). Hazards audited: kloop reads
// HbB while phaseB writes HbA (and vice versa) - disjoint; all pos/dpart
// RAW/WAR cross a barrier; w<4 is wave-uniform; barriers outside the branch.
//   I1: w<4 { kloopB; phaseC_B(t-1); phaseB_A } | w>=4 { phaseB_A; kloopB } ; bar
//   I2: w<4 { kloopA';phaseC_A(t);   phaseB_B } | w>=4 { phaseB_B; kloopA' } ; bar
// LDS 157,184 B; grid 768 (64 seqs/block), 1 block/CU, 8 waves (2/SIMD).

typedef __attribute__((ext_vector_type(8))) short short8;
typedef __bf16 bf16x8 __attribute__((ext_vector_type(8)));
typedef float f32x16 __attribute__((ext_vector_type(16)));
typedef float f32x4 __attribute__((ext_vector_type(4)));

#define HSTR 264               // Hb stride (bf16): 528B rows; balanced banks
#define NSEQ 32                // seqs per chain (2 chains per block)
#define WNL_SLICES 14          // wN k-slices staged in LDS (ks 14,15 from L2)
#define WHH3_ELEMS (24 * 16 * 64 * 8)  // 196608 = 768x256
#define WH0_ELEMS (8 * 20 * 64 * 8)    // 81920

static __device__ __forceinline__ unsigned short f2bf(float f) {
  unsigned u = __builtin_bit_cast(unsigned, f);
  u += 0x7fffu + ((u >> 16) & 1u);   // RNE
  return (unsigned short)(u >> 16);
}
static __device__ __forceinline__ float bf2f(unsigned short h) {
  unsigned u = ((unsigned)h) << 16;
  return __builtin_bit_cast(float, u);
}
static __device__ __forceinline__ bf16x8 ldfrag(const unsigned short* p) {
  return __builtin_bit_cast(bf16x8, *(const short8*)p);
}
static __device__ __forceinline__ float fsig(float x) {
  return __builtin_amdgcn_rcpf(1.f + __builtin_amdgcn_exp2f(-1.44269504f * x));
}
static __device__ __forceinline__ float ftanh(float x) {
  return 1.f - 2.f * __builtin_amdgcn_rcpf(1.f + __builtin_amdgcn_exp2f(2.88539008f * x));
}
static __device__ __forceinline__ float dpp16sum(float x) {
  x += __builtin_bit_cast(float, __builtin_amdgcn_update_dpp(0, __builtin_bit_cast(int, x), 0xB1, 0xF, 0xF, true));
  x += __builtin_bit_cast(float, __builtin_amdgcn_update_dpp(0, __builtin_bit_cast(int, x), 0x4E, 0xF, 0xF, true));
  x += __builtin_bit_cast(float, __builtin_amdgcn_update_dpp(0, __builtin_bit_cast(int, x), 0x141, 0xF, 0xF, true));
  x += __builtin_bit_cast(float, __builtin_amdgcn_update_dpp(0, __builtin_bit_cast(int, x), 0x140, 0xF, 0xF, true));
  return x;
}
// LDS-only barrier (r4-verified): no vmcnt drain; t-loop vmem = weight loads
// (compiler-waited before MFMA use) + out stores (fire-and-forget).
static __device__ __forceinline__ void bar_lgkm() {
  asm volatile("s_waitcnt lgkmcnt(0)\n\ts_barrier" ::: "memory");
}

// ---- prep: pack W_hh slice-major: [(g*8+w)*16 + ks][lane][8]  (r3-verified) ----
__global__ void prep_whh3_k(const float* __restrict__ Whh, unsigned short* __restrict__ Whhp3) {
  int i = blockIdx.x * 256 + threadIdx.x;
  if (i >= WHH3_ELEMS) return;
  int j = i & 7;
  int lane = (i >> 3) & 63;
  int rest = i >> 9;
  int ks = rest & 15;
  int sw = rest >> 4;
  int g = sw >> 3, w = sw & 7;
  int row = g * 256 + w * 32 + (lane & 31);
  int k = ks * 16 + ((lane >> 5) << 3) + j;
  Whhp3[i] = f2bf(Whh[row * 256 + k]);
}

// ---- prep: pack W_h0 (256 x 290, K padded to 320)  (r3-verified) ----
__global__ void prep_wh0_k(const float* __restrict__ Wh0, unsigned short* __restrict__ Wh0p) {
  int i = blockIdx.x * 256 + threadIdx.x;
  if (i >= WH0_ELEMS) return;
  int j = i & 7;
  int lane = (i >> 3) & 63;
  int rest = i >> 9;
  int ks = rest % 20;
  int nt = rest / 20;
  int row = nt * 32 + (lane & 31);
  int k = ks * 16 + ((lane >> 5) << 3) + j;
  float v = (k < 290) ? Wh0[row * 290 + k] : 0.f;
  Wh0p[i] = f2bf(v);
}

// ---- prep: per-h-unit params (r3-verified) ----
__global__ void prep_gp_k(const float* __restrict__ bih, const float* __restrict__ bhh,
                          const float* __restrict__ Wih, const float* __restrict__ Wout,
                          float* __restrict__ gpo) {
  int n = threadIdx.x;
  gpo[n * 12 + 0]  = bih[n] + bhh[n];
  gpo[n * 12 + 1]  = bih[n + 256] + bhh[n + 256];
  gpo[n * 12 + 2]  = bih[n + 512];
  gpo[n * 12 + 3]  = bhh[n + 512];
  gpo[n * 12 + 4]  = Wih[n * 2 + 0];
  gpo[n * 12 + 5]  = Wih[n * 2 + 1];
  gpo[n * 12 + 6]  = Wih[(n + 256) * 2 + 0];
  gpo[n * 12 + 7]  = Wih[(n + 256) * 2 + 1];
  gpo[n * 12 + 8]  = Wih[(n + 512) * 2 + 0];
  gpo[n * 12 + 9]  = Wih[(n + 512) * 2 + 1];
  gpo[n * 12 + 10] = Wout[n];
  gpo[n * 12 + 11] = Wout[256 + n];
}

// ---------------- main fused GRU, dual-chain + wave-order split ----------------
__global__ __launch_bounds__(512, 2) void gru_main_k(
    const float* __restrict__ ctx, const float* __restrict__ goals,
    const float* __restrict__ emb, const float* __restrict__ bh0,
    const float* __restrict__ bout,
    const unsigned short* __restrict__ Wh0p,
    const unsigned short* __restrict__ Whhp3,
    const float* __restrict__ gp,
    float* __restrict__ out) {
  __shared__ __align__(16) unsigned short wNl[8 * WNL_SLICES * 64 * 8]; // 114688 B
  __shared__ __align__(16) unsigned short HbA[NSEQ * HSTR];            // 16896 B
  __shared__ __align__(16) unsigned short HbB[NSEQ * HSTR];            // 16896 B
  __shared__ __align__(16) float dpartA[16 * NSEQ * 2];                // 4096 B
  __shared__ __align__(16) float dpartB[16 * NSEQ * 2];                // 4096 B
  __shared__ __align__(16) float posA[NSEQ * 2];                       // 256 B
  __shared__ __align__(16) float posB[NSEQ * 2];                       // 256 B
  // total 157,184 B <= 160 KiB; 1 block/CU, 8 waves (2/SIMD)

  const int tid = threadIdx.x;
  const int w = tid >> 6;
  const int l = tid & 63;
  const int l31 = l & 31;
  const int grp = l >> 5;
  const int seq0 = blockIdx.x * (2 * NSEQ);
  const int n0 = w * 32 + l31;

  // ---- stage wN slices 0..13 per wave into LDS, block-cooperative ----
  {
    short8* wdst = (short8*)wNl;
    const short8* wsrc = (const short8*)Whhp3;
    for (int f = tid; f < 8 * WNL_SLICES * 64; f += 512) {
      int ll = f & 63;
      int t2 = f >> 6;
      int ks = t2 % WNL_SLICES;
      int ww = t2 / WNL_SLICES;
      wdst[f] = wsrc[((16 + ww) * 16 + ks) * 64 + ll];   // g=2 region
    }
  }

  // ---------------- Phase 0: h0 = init_in @ W_h0^T + b_h0 (per chain) ----------------
  auto phase0 = [&](unsigned short* Hb, int sBase) {
    f32x16 acc0 = f32x16{};
    unsigned short* As = Hb;   // overlay staging, stride 176 (5632 shorts < 8448)
    for (int cc = 0; cc < 2; ++cc) {
      for (int i = tid; i < NSEQ * 160; i += 512) {
        int row = i / 160;
        int col = i - row * 160;
        int d = cc * 160 + col;
        int s = sBase + row;
        int b = s / 6;
        float v;
        if (d < 256)      v = ctx[b * 256 + d];
        else if (d < 258) v = goals[s * 2 + (d - 256)];
        else if (d < 290) v = emb[b * 32 + (d - 258)];
        else              v = 0.f;
        As[row * 176 + col] = f2bf(v);
      }
      __syncthreads();   // also orders the wNl staging writes (first pass)
      for (int ks = 0; ks < 10; ++ks) {
        bf16x8 bf = ldfrag(&Wh0p[((w * 20 + cc * 10 + ks) * 64 + l) * 8]);
        bf16x8 af = ldfrag(&As[l31 * 176 + ks * 16 + grp * 8]);
        acc0 = __builtin_amdgcn_mfma_f32_32x32x16_bf16(af, bf, acc0, 0, 0, 0);
      }
      __syncthreads();
    }
    // write h0 into Hb (C/D layout [m74/m101]); readers sync before t-loop
    float b0 = bh0[n0];
#pragma unroll
    for (int r = 0; r < 16; ++r) {
      int row = (r & 3) + 8 * (r >> 2) + 4 * grp;
      Hb[row * HSTR + n0] = f2bf(acc0[r] + b0);
    }
  };

  phase0(HbA, seq0);
  phase0(HbB, seq0 + NSEQ);
  if (tid < 2 * NSEQ) { posA[tid] = 0.f; posB[tid] = 0.f; }

  float brr, bzz, bin_, bhn, wr0, wr1, wz0, wz1, wn0, wn1, wo0, wo1;
  {
    f32x4 g0 = *(const f32x4*)&gp[n0 * 12];
    f32x4 g1 = *(const f32x4*)&gp[n0 * 12 + 4];
    f32x4 g2 = *(const f32x4*)&gp[n0 * 12 + 8];
    brr = g0[0]; bzz = g0[1]; bin_ = g0[2]; bhn = g0[3];
    wr0 = g1[0]; wr1 = g1[1]; wz0 = g1[2]; wz1 = g1[3];
    wn0 = g2[0]; wn1 = g2[1]; wo0 = g2[2]; wo1 = g2[3];
  }
  const float bo0 = bout[0], bo1 = bout[1];
  __syncthreads();   // h0 writes + pos init visible to all

  // Per-wave weight-stream base pointers (L2-resident, 393 KB set)
  const unsigned short* wRb = &Whhp3[((w * 16) * 64 + l) * 8];          // g=0
  const unsigned short* wZb = &Whhp3[(((8 + w) * 16) * 64 + l) * 8];    // g=1
  const unsigned short* wNg = &Whhp3[(((16 + w) * 16) * 64 + l) * 8];   // g=2

  // K-loop: A from Hb (LDS), wR/wZ streamed from L2, wN from LDS (+2 slices L2).
  // unroll 4 (NOT full): bounds scheduler load-hoisting to 16 loads (64 VGPRs)
  // -> spill-free (r12-verified: VGPR 108, WRITE = out only).
  auto kloop = [&](const unsigned short* Hb, f32x16& ar, f32x16& az, f32x16& an) {
    ar = f32x16{}; az = f32x16{}; an = f32x16{};
#pragma unroll 4
    for (int ks = 0; ks < 16; ++ks) {
      bf16x8 af = ldfrag(&Hb[l31 * HSTR + ks * 16 + grp * 8]);
      bf16x8 bR = ldfrag(&wRb[ks * 512]);
      bf16x8 bZ = ldfrag(&wZb[ks * 512]);
      bf16x8 bN = (ks < WNL_SLICES)
          ? ldfrag(&wNl[((w * WNL_SLICES + ks) * 64 + l) * 8])
          : ldfrag(&wNg[ks * 512]);
      ar = __builtin_amdgcn_mfma_f32_32x32x16_bf16(af, bR, ar, 0, 0, 0);
      az = __builtin_amdgcn_mfma_f32_32x32x16_bf16(af, bZ, az, 0, 0, 0);
      an = __builtin_amdgcn_mfma_f32_32x32x16_bf16(af, bN, an, 0, 0, 0);
    }
  };

  // Phase B: gates + h update (h via Hb/LDS, r6-verified) + delta partials
  auto phaseB = [&](const f32x16& ar, const f32x16& az, const f32x16& an,
                    float* posL, unsigned short* Hb, float* dpart) {
#pragma unroll
    for (int q2 = 0; q2 < 4; ++q2) {
      int sb = 8 * q2 + 4 * grp;
      f32x4 xyA = *(const f32x4*)&posL[sb * 2];
      f32x4 xyB = *(const f32x4*)&posL[sb * 2 + 4];
#pragma unroll
      for (int e = 0; e < 4; ++e) {
        int r = 4 * q2 + e;
        int s = sb + e;
        float x = (e == 0) ? xyA[0] : (e == 1) ? xyA[2] : (e == 2) ? xyB[0] : xyB[2];
        float y = (e == 0) ? xyA[1] : (e == 1) ? xyA[3] : (e == 2) ? xyB[1] : xyB[3];
        int ha = s * HSTR + n0;
        float h = bf2f(Hb[ha]);
        float rg = fsig(ar[r] + brr + x * wr0 + y * wr1);
        float zg = fsig(az[r] + bzz + x * wz0 + y * wz1);
        float ng = ftanh(fmaf(rg, an[r] + bhn, fmaf(x, wn0, fmaf(y, wn1, bin_))));
        float hnew = fmaf(zg, h - ng, ng);     // (1-z)*n + z*h
        Hb[ha] = f2bf(hnew);
        float dx = dpp16sum(hnew * wo0);
        float dy = dpp16sum(hnew * wo1);
        if ((l & 15) == 0) {
          int p16 = w * 2 + ((l >> 4) & 1);
          dpart[(p16 * NSEQ + s) * 2]     = dx;
          dpart[(p16 * NSEQ + s) * 2 + 1] = dy;
        }
      }
    }
  };

  // Phase C (one wave per chain): pos update + raw pred store
  auto phaseC = [&](float* posL, float* dpart, int sBase, int st, int tbase) {
    int tt = tid - tbase;
    if (tt >= 0 && tt < 2 * NSEQ) {
      int s = tt >> 1, c = tt & 1;
      float d = (c == 0) ? bo0 : bo1;
#pragma unroll
      for (int q = 0; q < 16; ++q) d += dpart[(q * NSEQ + s) * 2 + c];
      float p = posL[tt] + d;
      posL[tt] = p;
      out[((sBase + s) * 30 + st) * 2 + c] = p;
    }
  };

  // ---------------- T recurrent steps, wave-order-split pipelined ----------------
  f32x16 arA, azA, anA, arB, azB, anB;
  kloop(HbA, arA, azA, anA);              // Kloop_A(0), all waves

#pragma unroll 1
  for (int t = 0; t < 30; ++t) {
    // I1: kloop_B(t) [reads HbB] || phaseB_A(t) [writes HbA] — disjoint buffers.
    // w<4 leads with MFMA, w>=4 leads with VALU: each SIMD co-issues both pipes.
    if (w < 4) {
      kloop(HbB, arB, azB, anB);
      if (t > 0) phaseC(posB, dpartB, seq0 + NSEQ, t - 1, 64);   // wave 1
      phaseB(arA, azA, anA, posA, HbA, dpartA);
    } else {
      phaseB(arA, azA, anA, posA, HbA, dpartA);
      kloop(HbB, arB, azB, anB);
    }
    bar_lgkm();   // HbA writes + dpartA + posB visible; HbB reads retired
    // I2: kloop_A(t+1) [reads HbA] || phaseB_B(t) [writes HbB] — disjoint.
    if (w < 4) {
      if (t < 29) kloop(HbA, arA, azA, anA);
      phaseC(posA, dpartA, seq0, t, 0);                          // wave 0
      phaseB(arB, azB, anB, posB, HbB, dpartB);
    } else {
      phaseB(arB, azB, anB, posB, HbB, dpartB);
      if (t < 29) kloop(HbA, arA, azA, anA);
    }
    bar_lgkm();   // HbB writes + dpartB + posA visible; HbA reads retired
  }
  // epilogue: phaseC_B(29)
  phaseC(posB, dpartB, seq0 + NSEQ, 29, 64);
}

// ---- correction: out = pred + (goal - pred_T) * (t+1)/30, in place (verified) ----
__global__ void corr_k(float* __restrict__ out, const float* __restrict__ goals) {
  __shared__ float buf[240];
  int tid = threadIdx.x;
  int s0 = blockIdx.x * 4;
  float v = 0.f;
  if (tid < 240) { v = out[s0 * 60 + tid]; buf[tid] = v; }
  __syncthreads();
  if (tid < 240) {
    int sl = tid / 60;
    int rem = tid - sl * 60;
    int t = rem >> 1, c = rem & 1;
    float pT = buf[sl * 60 + 58 + c];
    float g = goals[(s0 + sl) * 2 + c];
    out[s0 * 60 + tid] = v + (g - pT) * ((float)(t + 1) * (1.f / 30.f));
  }
}

extern "C" void kernel_launch(void* const* d_in, const int* in_sizes, int n_in,
                              void* d_out, int out_size, void* d_ws, size_t ws_size,
                              hipStream_t stream) {
  (void)in_sizes; (void)n_in; (void)out_size; (void)ws_size;
  const float* ctx  = (const float*)d_in[0];
  const float* goals= (const float*)d_in[1];
  const float* emb  = (const float*)d_in[2];
  const float* Wh0  = (const float*)d_in[3];
  const float* bh0  = (const float*)d_in[4];
  const float* Wih  = (const float*)d_in[5];
  const float* Whh  = (const float*)d_in[6];
  const float* bih  = (const float*)d_in[7];
  const float* bhh  = (const float*)d_in[8];
  const float* Wout = (const float*)d_in[9];
  const float* bout = (const float*)d_in[10];
  float* out = (float*)d_out;

  unsigned short* Whhp3 = (unsigned short*)d_ws;                       // 393216 B
  unsigned short* Wh0p  = (unsigned short*)((char*)d_ws + 393216);     // 163840 B
  float* gpo = (float*)((char*)d_ws + 393216 + 163840);                // 12288 B

  hipLaunchKernelGGL(prep_whh3_k, dim3(768), dim3(256), 0, stream, Whh, Whhp3);
  hipLaunchKernelGGL(prep_wh0_k, dim3(320), dim3(256), 0, stream, Wh0, Wh0p);
  hipLaunchKernelGGL(prep_gp_k, dim3(1), dim3(256), 0, stream, bih, bhh, Wih, Wout, gpo);
  hipLaunchKernelGGL(gru_main_k, dim3(768), dim3(512), 0, stream,
                     ctx, goals, emb, bh0, bout, Wh0p, Whhp3, gpo, out);
  hipLaunchKernelGGL(corr_k, dim3(12288), dim3(256), 0, stream, out, goals);
}

// Round 8
// 1053.757 us; speedup vs baseline: 2.5574x; 1.1064x over previous
//
#include <hip/hip_runtime.h>

// TrajectoryDecoder r14 = r6 structure (verified, 985us) + 2-blocks/CU occupancy.
// r12/r13 post-mortem: dual-chain / wave-order overlap CANNOT help — each wave
// executes kloop+phaseB serially; cross-wave co-issue only fills stalls. Model
// from counters: per block-t-step 14.3k cyc = VALU-issue 54% + MFMA 25% + idle
// 21%. The lever is OCCUPANCY (fill the idle + push VALU toward 100%): we are
// LDS-capped at 1 block/CU by wNl (131 KB). r14: stage only 7/16 wN slices
// (56 KB), stream slices 7..15 from L2 like wR/wZ. LDS = 78,592 B -> 2 blocks/
// CU = 4 waves/SIMD. L2 stream: 41 KB/wave/kloop x 16 waves = 656 KB/CU/t =
// ~11.7k cyc < doubled VALU-issue 15.4k -> VALU-bound at high utilization.
// Register wall: 4/SIMD => 128 regs/wave: 48 acc + VGPR<=80, enforced by
// __launch_bounds__(512,4); kloop unroll 2 bounds frag/addr liveness.
// Everything else is the r6-verified single-chain loop (kloop; bar; phaseB;
// bar; phaseC). Verification: OccupancyPercent ~45, WRITE_SIZE ~11.5 MB
// (balloon = spill = revert knobs next round).

typedef __attribute__((ext_vector_type(8))) short short8;
typedef __bf16 bf16x8 __attribute__((ext_vector_type(8)));
typedef float f32x16 __attribute__((ext_vector_type(16)));
typedef float f32x4 __attribute__((ext_vector_type(4)));

#define HSTR 264               // Hb stride (bf16): 528B rows; balanced banks
#define NSEQ_BLK 32
#define WNL_SLICES 7           // wN k-slices staged in LDS (ks 7..15 from L2)
#define WHH3_ELEMS (24 * 16 * 64 * 8)  // 196608 = 768x256
#define WH0_ELEMS (8 * 20 * 64 * 8)    // 81920

static __device__ __forceinline__ unsigned short f2bf(float f) {
  unsigned u = __builtin_bit_cast(unsigned, f);
  u += 0x7fffu + ((u >> 16) & 1u);   // RNE
  return (unsigned short)(u >> 16);
}
static __device__ __forceinline__ float bf2f(unsigned short h) {
  unsigned u = ((unsigned)h) << 16;
  return __builtin_bit_cast(float, u);
}
static __device__ __forceinline__ bf16x8 ldfrag(const unsigned short* p) {
  return __builtin_bit_cast(bf16x8, *(const short8*)p);
}
static __device__ __forceinline__ float fsig(float x) {
  return __builtin_amdgcn_rcpf(1.f + __builtin_amdgcn_exp2f(-1.44269504f * x));
}
static __device__ __forceinline__ float ftanh(float x) {
  return 1.f - 2.f * __builtin_amdgcn_rcpf(1.f + __builtin_amdgcn_exp2f(2.88539008f * x));
}
static __device__ __forceinline__ float dpp16sum(float x) {
  x += __builtin_bit_cast(float, __builtin_amdgcn_update_dpp(0, __builtin_bit_cast(int, x), 0xB1, 0xF, 0xF, true));
  x += __builtin_bit_cast(float, __builtin_amdgcn_update_dpp(0, __builtin_bit_cast(int, x), 0x4E, 0xF, 0xF, true));
  x += __builtin_bit_cast(float, __builtin_amdgcn_update_dpp(0, __builtin_bit_cast(int, x), 0x141, 0xF, 0xF, true));
  x += __builtin_bit_cast(float, __builtin_amdgcn_update_dpp(0, __builtin_bit_cast(int, x), 0x140, 0xF, 0xF, true));
  return x;
}
// LDS-only barrier (r4-verified): no vmcnt drain; t-loop vmem = weight loads
// (compiler-waited before MFMA use) + out stores (fire-and-forget).
static __device__ __forceinline__ void bar_lgkm() {
  asm volatile("s_waitcnt lgkmcnt(0)\n\ts_barrier" ::: "memory");
}

// ---- prep: pack W_hh slice-major: [(g*8+w)*16 + ks][lane][8]  (r3-verified) ----
__global__ void prep_whh3_k(const float* __restrict__ Whh, unsigned short* __restrict__ Whhp3) {
  int i = blockIdx.x * 256 + threadIdx.x;
  if (i >= WHH3_ELEMS) return;
  int j = i & 7;
  int lane = (i >> 3) & 63;
  int rest = i >> 9;
  int ks = rest & 15;
  int sw = rest >> 4;
  int g = sw >> 3, w = sw & 7;
  int row = g * 256 + w * 32 + (lane & 31);
  int k = ks * 16 + ((lane >> 5) << 3) + j;
  Whhp3[i] = f2bf(Whh[row * 256 + k]);
}

// ---- prep: pack W_h0 (256 x 290, K padded to 320)  (r3-verified) ----
__global__ void prep_wh0_k(const float* __restrict__ Wh0, unsigned short* __restrict__ Wh0p) {
  int i = blockIdx.x * 256 + threadIdx.x;
  if (i >= WH0_ELEMS) return;
  int j = i & 7;
  int lane = (i >> 3) & 63;
  int rest = i >> 9;
  int ks = rest % 20;
  int nt = rest / 20;
  int row = nt * 32 + (lane & 31);
  int k = ks * 16 + ((lane >> 5) << 3) + j;
  float v = (k < 290) ? Wh0[row * 290 + k] : 0.f;
  Wh0p[i] = f2bf(v);
}

// ---- prep: per-h-unit params (r3-verified) ----
__global__ void prep_gp_k(const float* __restrict__ bih, const float* __restrict__ bhh,
                          const float* __restrict__ Wih, const float* __restrict__ Wout,
                          float* __restrict__ gpo) {
  int n = threadIdx.x;
  gpo[n * 12 + 0]  = bih[n] + bhh[n];
  gpo[n * 12 + 1]  = bih[n + 256] + bhh[n + 256];
  gpo[n * 12 + 2]  = bih[n + 512];
  gpo[n * 12 + 3]  = bhh[n + 512];
  gpo[n * 12 + 4]  = Wih[n * 2 + 0];
  gpo[n * 12 + 5]  = Wih[n * 2 + 1];
  gpo[n * 12 + 6]  = Wih[(n + 256) * 2 + 0];
  gpo[n * 12 + 7]  = Wih[(n + 256) * 2 + 1];
  gpo[n * 12 + 8]  = Wih[(n + 512) * 2 + 0];
  gpo[n * 12 + 9]  = Wih[(n + 512) * 2 + 1];
  gpo[n * 12 + 10] = Wout[n];
  gpo[n * 12 + 11] = Wout[256 + n];
}

// ---------------- main fused GRU (r6 structure, 2 blocks/CU) ----------------
__global__ __launch_bounds__(512, 4) void gru_main_k(
    const float* __restrict__ ctx, const float* __restrict__ goals,
    const float* __restrict__ emb, const float* __restrict__ bh0,
    const float* __restrict__ bout,
    const unsigned short* __restrict__ Wh0p,
    const unsigned short* __restrict__ Whhp3,
    const float* __restrict__ gp,
    float* __restrict__ out) {
  __shared__ __align__(16) unsigned short wNl[8 * WNL_SLICES * 64 * 8]; // 57344 B
  __shared__ __align__(16) unsigned short Hb[NSEQ_BLK * HSTR];          // 16896 B
  __shared__ __align__(16) float dpart[16 * NSEQ_BLK * 2];              // 4096 B
  __shared__ __align__(16) float posL[NSEQ_BLK * 2];                    // 256 B
  // total 78,592 B -> 2 blocks/CU (157,184 <= 163,840); 16 waves/CU (4/SIMD)

  const int tid = threadIdx.x;
  const int w = tid >> 6;
  const int l = tid & 63;
  const int l31 = l & 31;
  const int grp = l >> 5;
  const int seq0 = blockIdx.x * NSEQ_BLK;
  const int n0 = w * 32 + l31;

  // ---- stage wN slices 0..6 per wave into LDS, block-cooperative ----
  {
    short8* wdst = (short8*)wNl;
    const short8* wsrc = (const short8*)Whhp3;
    for (int f = tid; f < 8 * WNL_SLICES * 64; f += 512) {
      int ll = f & 63;
      int t2 = f >> 6;
      int ks = t2 % WNL_SLICES;
      int ww = t2 / WNL_SLICES;
      wdst[f] = wsrc[((16 + ww) * 16 + ks) * 64 + ll];   // g=2 region
    }
  }

  // ---------------- Phase 0: h0 = init_in @ W_h0^T + b_h0 (r6-verified) ----------------
  f32x16 acc0 = f32x16{};
  {
    unsigned short* As = Hb;   // overlay staging, stride 176 (5632 shorts < 8448)
    for (int cc = 0; cc < 2; ++cc) {
      for (int i = tid; i < NSEQ_BLK * 160; i += 512) {
        int row = i / 160;
        int col = i - row * 160;
        int d = cc * 160 + col;
        int s = seq0 + row;
        int b = s / 6;
        float v;
        if (d < 256)      v = ctx[b * 256 + d];
        else if (d < 258) v = goals[s * 2 + (d - 256)];
        else if (d < 290) v = emb[b * 32 + (d - 258)];
        else              v = 0.f;
        As[row * 176 + col] = f2bf(v);
      }
      __syncthreads();   // also orders the wNl staging writes (cc=0)
      for (int ks = 0; ks < 10; ++ks) {
        bf16x8 bf = ldfrag(&Wh0p[((w * 20 + cc * 10 + ks) * 64 + l) * 8]);
        bf16x8 af = ldfrag(&As[l31 * 176 + ks * 16 + grp * 8]);
        acc0 = __builtin_amdgcn_mfma_f32_32x32x16_bf16(af, bf, acc0, 0, 0, 0);
      }
      __syncthreads();
    }
  }
  {
    float b0 = bh0[n0];
#pragma unroll
    for (int r = 0; r < 16; ++r) {
      int row = (r & 3) + 8 * (r >> 2) + 4 * grp;   // C/D layout [m74/m101]
      Hb[row * HSTR + n0] = f2bf(acc0[r] + b0);
    }
  }
  if (tid < 2 * NSEQ_BLK) posL[tid] = 0.f;

  float brr, bzz, bin_, bhn, wr0, wr1, wz0, wz1, wn0, wn1, wo0, wo1;
  {
    f32x4 g0 = *(const f32x4*)&gp[n0 * 12];
    f32x4 g1 = *(const f32x4*)&gp[n0 * 12 + 4];
    f32x4 g2 = *(const f32x4*)&gp[n0 * 12 + 8];
    brr = g0[0]; bzz = g0[1]; bin_ = g0[2]; bhn = g0[3];
    wr0 = g1[0]; wr1 = g1[1]; wz0 = g1[2]; wz1 = g1[3];
    wn0 = g2[0]; wn1 = g2[1]; wo0 = g2[2]; wo1 = g2[3];
  }
  const float bo0 = bout[0], bo1 = bout[1];
  __syncthreads();

  // Per-wave weight-stream base pointers (L2-resident, 384 KB set)
  const unsigned short* wRb = &Whhp3[((w * 16) * 64 + l) * 8];          // g=0
  const unsigned short* wZb = &Whhp3[(((8 + w) * 16) * 64 + l) * 8];    // g=1
  const unsigned short* wNg = &Whhp3[(((16 + w) * 16) * 64 + l) * 8];   // g=2

  // ---------------- T recurrent steps (r6-verified loop body) ----------------
#pragma unroll 1
  for (int t = 0; t < 30; ++t) {
    f32x16 ar = f32x16{}, az = f32x16{}, an = f32x16{};

    // K-loop: A from Hb (LDS), wR/wZ + wN-tail streamed from L2, wN 0..6 LDS.
    // unroll 2: bounds frag/addr liveness for the 128-reg cap (4 waves/SIMD).
#pragma unroll 2
    for (int ks = 0; ks < 16; ++ks) {
      bf16x8 af = ldfrag(&Hb[l31 * HSTR + ks * 16 + grp * 8]);
      bf16x8 bR = ldfrag(&wRb[ks * 512]);
      bf16x8 bZ = ldfrag(&wZb[ks * 512]);
      bf16x8 bN = (ks < WNL_SLICES)
          ? ldfrag(&wNl[((w * WNL_SLICES + ks) * 64 + l) * 8])
          : ldfrag(&wNg[ks * 512]);
      ar = __builtin_amdgcn_mfma_f32_32x32x16_bf16(af, bR, ar, 0, 0, 0);
      az = __builtin_amdgcn_mfma_f32_32x32x16_bf16(af, bZ, az, 0, 0, 0);
      an = __builtin_amdgcn_mfma_f32_32x32x16_bf16(af, bN, an, 0, 0, 0);
    }
    bar_lgkm();   // barrier1: Hb reads done; posL(t-1) final

    // Phase B: gates + h update + delta partials (r3/r6-verified structure)
#pragma unroll
    for (int q2 = 0; q2 < 4; ++q2) {
      int sb = 8 * q2 + 4 * grp;
      f32x4 xyA = *(const f32x4*)&posL[sb * 2];
      f32x4 xyB = *(const f32x4*)&posL[sb * 2 + 4];
#pragma unroll
      for (int e = 0; e < 4; ++e) {
        int r = 4 * q2 + e;
        int s = sb + e;
        float x = (e == 0) ? xyA[0] : (e == 1) ? xyA[2] : (e == 2) ? xyB[0] : xyB[2];
        float y = (e == 0) ? xyA[1] : (e == 1) ? xyA[3] : (e == 2) ? xyB[1] : xyB[3];
        int ha = s * HSTR + n0;
        float h = bf2f(Hb[ha]);
        float rg = fsig(ar[r] + brr + x * wr0 + y * wr1);
        float zg = fsig(az[r] + bzz + x * wz0 + y * wz1);
        float ng = ftanh(fmaf(rg, an[r] + bhn, fmaf(x, wn0, fmaf(y, wn1, bin_))));
        float hnew = fmaf(zg, h - ng, ng);     // (1-z)*n + z*h
        Hb[ha] = f2bf(hnew);
        float dx = dpp16sum(hnew * wo0);
        float dy = dpp16sum(hnew * wo1);
        if ((l & 15) == 0) {
          int p16 = w * 2 + ((l >> 4) & 1);
          dpart[(p16 * NSEQ_BLK + s) * 2]     = dx;
          dpart[(p16 * NSEQ_BLK + s) * 2 + 1] = dy;
        }
      }
    }
    bar_lgkm();   // barrier2: Hb h-writes + dpart visible

    // Phase C (wave 0): pos update + raw pred store
    if (tid < 2 * NSEQ_BLK) {
      int s = tid >> 1, c = tid & 1;
      float d = (c == 0) ? bo0 : bo1;
#pragma unroll
      for (int q = 0; q < 16; ++q) d += dpart[(q * NSEQ_BLK + s) * 2 + c];
      float p = posL[tid] + d;
      posL[tid] = p;
      out[((seq0 + s) * 30 + t) * 2 + c] = p;
    }
  }
}

// ---- correction: out = pred + (goal - pred_T) * (t+1)/30, in place (verified) ----
__global__ void corr_k(float* __restrict__ out, const float* __restrict__ goals) {
  __shared__ float buf[240];
  int tid = threadIdx.x;
  int s0 = blockIdx.x * 4;
  float v = 0.f;
  if (tid < 240) { v = out[s0 * 60 + tid]; buf[tid] = v; }
  __syncthreads();
  if (tid < 240) {
    int sl = tid / 60;
    int rem = tid - sl * 60;
    int t = rem >> 1, c = rem & 1;
    float pT = buf[sl * 60 + 58 + c];
    float g = goals[(s0 + sl) * 2 + c];
    out[s0 * 60 + tid] = v + (g - pT) * ((float)(t + 1) * (1.f / 30.f));
  }
}

extern "C" void kernel_launch(void* const* d_in, const int* in_sizes, int n_in,
                              void* d_out, int out_size, void* d_ws, size_t ws_size,
                              hipStream_t stream) {
  (void)in_sizes; (void)n_in; (void)out_size; (void)ws_size;
  const float* ctx  = (const float*)d_in[0];
  const float* goals= (const float*)d_in[1];
  const float* emb  = (const float*)d_in[2];
  const float* Wh0  = (const float*)d_in[3];
  const float* bh0  = (const float*)d_in[4];
  const float* Wih  = (const float*)d_in[5];
  const float* Whh  = (const float*)d_in[6];
  const float* bih  = (const float*)d_in[7];
  const float* bhh  = (const float*)d_in[8];
  const float* Wout = (const float*)d_in[9];
  const float* bout = (const float*)d_in[10];
  float* out = (float*)d_out;

  unsigned short* Whhp3 = (unsigned short*)d_ws;                       // 393216 B
  unsigned short* Wh0p  = (unsigned short*)((char*)d_ws + 393216);     // 163840 B
  float* gpo = (float*)((char*)d_ws + 393216 + 163840);                // 12288 B

  hipLaunchKernelGGL(prep_whh3_k, dim3(768), dim3(256), 0, stream, Whh, Whhp3);
  hipLaunchKernelGGL(prep_wh0_k, dim3(320), dim3(256), 0, stream, Wh0, Wh0p);
  hipLaunchKernelGGL(prep_gp_k, dim3(1), dim3(256), 0, stream, bih, bhh, Wih, Wout, gpo);
  hipLaunchKernelGGL(gru_main_k, dim3(1536), dim3(512), 0, stream,
                     ctx, goals, emb, bh0, bout, Wh0p, Whhp3, gpo, out);
  hipLaunchKernelGGL(corr_k, dim3(12288), dim3(256), 0, stream, out, goals);
}